// Round 4
// baseline (9929.679 us; speedup 1.0000x reference)
//
#include <hip/hip_runtime.h>
#include <hip/hip_cooperative_groups.h>
#include <math.h>

namespace cg = cooperative_groups;

// Grid-RNN (WhileOpGridLSTMNet): DEPTH=2, SRC=TRG=32, B=32, H=256
// out[d][i][j][c][b][h], c=0:HX, c=1:HY
#define SRCN 32
#define TRGN 32
#define BN   32
#define HN   256
#define BH   (BN*HN)          // 8192 floats per (cell,channel)
#define CELL (2*BH)           // 16384 floats per cell
#define DSZ  (SRCN*TRGN*CELL) // floats per depth
#define NB    1024            // blocks (4 blocks/CU guaranteed: LDS=0, vgpr<=128)
#define NWAVE (NB*4)

__device__ __forceinline__ int ncd(int t) { // cells on anti-diagonal t (0..62)
    int a = t + 1, b = 63 - t;
    int m = a < b ? a : b;
    return m < 32 ? m : 32;
}

// Static schedule, one grid.sync per step:
//   phase A: proj0 (xp0[i]=src[i]@W0, yp0[j]=trg[j]@W0)
//   step s=0..64: layer-0 rec diag s  |  layer-1 rec diag s-2 (proj1 folded in)
// Wave-item = (cell, 64 h-cols, 8 b-rows). State reads are wave-uniform
// broadcast loads; weights lane-coalesced. bq-items of a (cell,h64) sit on
// the 4 waves of one block -> L1 weight reuse.
__global__ __launch_bounds__(256, 4) void grid_rnn_coop(
    const float* __restrict__ src, const float* __restrict__ trg,
    const float* __restrict__ W, const float* __restrict__ U,
    const float* __restrict__ bias, float* __restrict__ out,
    float* __restrict__ xp0, float* __restrict__ yp0,
    const float* __restrict__ zbuf)
{
    cg::grid_group grid = cg::this_grid();
    const int lane = threadIdx.x & 63;
    const int gw   = blockIdx.x * 4 + (threadIdx.x >> 6);

    // ---- phase A: proj0 (64 slices x 16 items) ----
    for (int it = gw; it < 64 * 16; it += NWAVE) {
        const int slice = it >> 4, sub = it & 15;
        const int h  = ((sub >> 2) << 6) + lane;
        const int r0 = (sub & 3) * 8;
        const float* xin = (slice < 32) ? src + (size_t)slice * BH
                                        : trg + (size_t)(slice - 32) * BH;
        float* dst = (slice < 32) ? xp0 + (size_t)slice * BH
                                  : yp0 + (size_t)(slice - 32) * BH;
        const float* wc = W + h;            // W0 column h
        const float* xr = xin + r0 * 256;
        float acc[8] = {0,0,0,0,0,0,0,0};
        for (int k = 0; k < 256; k += 4) {
            float w0 = wc[(k+0)*256], w1 = wc[(k+1)*256];
            float w2 = wc[(k+2)*256], w3 = wc[(k+3)*256];
#pragma unroll
            for (int b = 0; b < 8; ++b) {
                float4 xv = *(const float4*)(xr + b * 256 + k);
                acc[b] += xv.x*w0 + xv.y*w1 + xv.z*w2 + xv.w*w3;
            }
        }
#pragma unroll
        for (int b = 0; b < 8; ++b) dst[(r0 + b) * 256 + h] = acc[b];
    }
    grid.sync();

    // ---- phase B: 65 wavefront steps ----
    for (int s = 0; s < 65; ++s) {
        const int n0 = (s <= 62) ? ncd(s) : 0;
        const int t1 = s - 2;
        const int n1 = (t1 >= 0) ? ncd(t1) : 0;
        const int total = (n0 + n1) * 16;

        for (int it = gw; it < total; it += NWAVE) {
            const int ci = it >> 4, sub = it & 15;
            const int h  = ((sub >> 2) << 6) + lane;
            const int r0 = (sub & 3) * 8;
            int d, i, j;
            if (ci < n0) {
                d = 0; int i0 = s - 31; if (i0 < 0) i0 = 0;
                i = i0 + ci; j = s - i;
            } else {
                d = 1; int c = ci - n0; int i0 = t1 - 31; if (i0 < 0) i0 = 0;
                i = i0 + c; j = t1 - i;
            }
            float* oD = out + (size_t)d * DSZ;
            const size_t cOff = (size_t)(i * 32 + j) * CELL;
            // state streams at row r0 (zbuf for missing neighbors: no selects)
            const float* sx = (i > 0) ? oD + cOff - 32 * CELL + r0 * 256 : zbuf;
            const float* ph = (j > 0) ? oD + cOff - CELL + r0 * 256      : zbuf;
            const float* uxc = U + (size_t)d * 131072 + h;  // Ux col h
            const float* uyc = uxc + 65536;                 // Uy col h

            float accT[8] = {0,0,0,0,0,0,0,0};
            for (int k = 0; k < 256; k += 4) {
                float x0 = uxc[(k+0)*256], x1 = uxc[(k+1)*256];
                float x2 = uxc[(k+2)*256], x3 = uxc[(k+3)*256];
                float y0 = uyc[(k+0)*256], y1 = uyc[(k+1)*256];
                float y2 = uyc[(k+2)*256], y3 = uyc[(k+3)*256];
#pragma unroll
                for (int b = 0; b < 8; ++b) {
                    float4 sv = *(const float4*)(sx + b * 256 + k);
                    float4 pv = *(const float4*)(ph + b * 256 + k);
                    accT[b] += sv.x*x0 + sv.y*x1 + sv.z*x2 + sv.w*x3
                             + pv.x*y0 + pv.y*y1 + pv.z*y2 + pv.w*y3;
                }
            }
            const float bv = bias[d * 256 + h];
            float* oHX = oD + cOff;
            float* oHY = oHX + BH;

            if (d == 0) {
                const float* xr = xp0 + (size_t)i * BH + r0 * 256 + h;
                const float* yr = yp0 + (size_t)j * BH + r0 * 256 + h;
#pragma unroll
                for (int b = 0; b < 8; ++b) {
                    float tmp = accT[b] + bv;
                    oHX[(r0+b)*256 + h] = tanhf(xr[b*256] + tmp);
                    oHY[(r0+b)*256 + h] = tanhf(yr[b*256] + tmp);
                }
            } else {
                // folded proj1: accX = HX0[cell]@W1, accY = HY0[cell]@W1
                const float* w1c  = W + 65536 + h;
                const float* hx0r = out + cOff + r0 * 256;  // layer-0 outputs
                const float* hy0r = hx0r + BH;
                float accX[8] = {0,0,0,0,0,0,0,0};
                float accY[8] = {0,0,0,0,0,0,0,0};
                for (int k = 0; k < 256; k += 4) {
                    float w0 = w1c[(k+0)*256], w1 = w1c[(k+1)*256];
                    float w2 = w1c[(k+2)*256], w3 = w1c[(k+3)*256];
#pragma unroll
                    for (int b = 0; b < 8; ++b) {
                        float4 xv = *(const float4*)(hx0r + b * 256 + k);
                        float4 yv = *(const float4*)(hy0r + b * 256 + k);
                        accX[b] += xv.x*w0 + xv.y*w1 + xv.z*w2 + xv.w*w3;
                        accY[b] += yv.x*w0 + yv.y*w1 + yv.z*w2 + yv.w*w3;
                    }
                }
#pragma unroll
                for (int b = 0; b < 8; ++b) {
                    float tmp = accT[b] + bv;
                    oHX[(r0+b)*256 + h] = tanhf(accX[b] + tmp);
                    oHY[(r0+b)*256 + h] = tanhf(accY[b] + tmp);
                }
            }
        }
        grid.sync();
    }
}

// ===========================================================================
// Fallback (round-1, proven 3.78ms): used if coop launch is rejected.
// ===========================================================================
__global__ __launch_bounds__(256) void proj0_kernel(
    const float* __restrict__ src, const float* __restrict__ trg,
    const float* __restrict__ W0, float* __restrict__ Xp0, float* __restrict__ Yp0)
{
    __shared__ float xs[BH];
    int blk = blockIdx.x >> 2, tile = blockIdx.x & 3;
    const float* X; float* P;
    if (blk < SRCN) { X = src + blk * BH; P = Xp0 + blk * BH; }
    else            { X = trg + (blk - SRCN) * BH; P = Yp0 + (blk - SRCN) * BH; }
    int tid = threadIdx.x;
    { const float4* x4 = (const float4*)X; float4* s4 = (float4*)xs;
#pragma unroll
      for (int r = 0; r < 8; ++r) s4[tid + r * 256] = x4[tid + r * 256]; }
    __syncthreads();
    int h = tile * 64 + (tid & 63), bg = tid >> 6;
    float acc[8] = {0,0,0,0,0,0,0,0};
    for (int k = 0; k < HN; k += 4) {
        float w0 = W0[(k+0)*HN+h], w1 = W0[(k+1)*HN+h], w2 = W0[(k+2)*HN+h], w3 = W0[(k+3)*HN+h];
#pragma unroll
        for (int bb = 0; bb < 8; ++bb) {
            int b = bg * 8 + bb;
            float4 xv = *(const float4*)&xs[b * HN + k];
            acc[bb] += xv.x*w0 + xv.y*w1 + xv.z*w2 + xv.w*w3;
        }
    }
#pragma unroll
    for (int bb = 0; bb < 8; ++bb) P[(bg*8+bb)*HN + h] = acc[bb];
}

__global__ __launch_bounds__(256) void proj1_kernel(
    float* __restrict__ out, const float* __restrict__ W1)
{
    __shared__ float hxs[BH];
    __shared__ float hys[BH];
    int cell = blockIdx.x >> 2, tile = blockIdx.x & 3;
    const float* hx0 = out + (size_t)cell * CELL;
    const float* hy0 = hx0 + BH;
    float* xp1 = out + (size_t)DSZ + (size_t)cell * CELL;
    float* yp1 = xp1 + BH;
    int tid = threadIdx.x;
    { const float4* a4 = (const float4*)hx0; const float4* b4 = (const float4*)hy0;
      float4* sa = (float4*)hxs; float4* sb = (float4*)hys;
#pragma unroll
      for (int r = 0; r < 8; ++r) { sa[tid+r*256] = a4[tid+r*256]; sb[tid+r*256] = b4[tid+r*256]; } }
    __syncthreads();
    int h = tile * 64 + (tid & 63), bg = tid >> 6;
    float ax[8] = {0,0,0,0,0,0,0,0}, ay[8] = {0,0,0,0,0,0,0,0};
    for (int k = 0; k < HN; k += 4) {
        float w0 = W1[(k+0)*HN+h], w1 = W1[(k+1)*HN+h], w2 = W1[(k+2)*HN+h], w3 = W1[(k+3)*HN+h];
#pragma unroll
        for (int bb = 0; bb < 8; ++bb) {
            int b = bg * 8 + bb;
            float4 xv = *(const float4*)&hxs[b*HN+k];
            float4 yv = *(const float4*)&hys[b*HN+k];
            ax[bb] += xv.x*w0 + xv.y*w1 + xv.z*w2 + xv.w*w3;
            ay[bb] += yv.x*w0 + yv.y*w1 + yv.z*w2 + yv.w*w3;
        }
    }
#pragma unroll
    for (int bb = 0; bb < 8; ++bb) {
        int b = bg * 8 + bb;
        xp1[b*HN+h] = ax[bb]; yp1[b*HN+h] = ay[bb];
    }
}

__global__ __launch_bounds__(256) void diag_kernel(
    float* out, const float* __restrict__ U, const float* __restrict__ bias,
    const float* __restrict__ Xp0, const float* __restrict__ Yp0, int d, int t)
{
    __shared__ float sxs[BH];
    __shared__ float phs[BH];
    int c = blockIdx.x >> 2, tile = blockIdx.x & 3;
    int i0 = t - (TRGN - 1); if (i0 < 0) i0 = 0;
    int i = i0 + c, j = t - i;
    const float* Ux = U + d * (2 * HN * HN);
    const float* Uy = Ux + HN * HN;
    float* outD = out + (size_t)d * DSZ;
    const float* sx = (i > 0) ? outD + (size_t)((i-1)*TRGN + j) * CELL : nullptr;
    const float* ph = (j > 0) ? outD + (size_t)(i*TRGN + (j-1)) * CELL : nullptr;
    float* oHX = outD + (size_t)(i*TRGN + j) * CELL;
    float* oHY = oHX + BH;
    const float* xp = d ? oHX : (Xp0 + i * BH);
    const float* yp = d ? oHY : (Yp0 + j * BH);
    const float* bd = bias + d * HN;
    int tid = threadIdx.x;
    { const float4* s4 = (const float4*)sx; const float4* p4 = (const float4*)ph;
      float4* d1 = (float4*)sxs; float4* d2 = (float4*)phs;
      float4 z = make_float4(0.f,0.f,0.f,0.f);
#pragma unroll
      for (int r = 0; r < 8; ++r) { int idx = tid + r*256; d1[idx] = sx ? s4[idx] : z; d2[idx] = ph ? p4[idx] : z; } }
    __syncthreads();
    int h = tile * 64 + (tid & 63), bg = tid >> 6;
    float acc[8] = {0,0,0,0,0,0,0,0};
    for (int k = 0; k < HN; k += 4) {
        float ux0 = Ux[(k+0)*HN+h], ux1 = Ux[(k+1)*HN+h], ux2 = Ux[(k+2)*HN+h], ux3 = Ux[(k+3)*HN+h];
        float uy0 = Uy[(k+0)*HN+h], uy1 = Uy[(k+1)*HN+h], uy2 = Uy[(k+2)*HN+h], uy3 = Uy[(k+3)*HN+h];
#pragma unroll
        for (int bb = 0; bb < 8; ++bb) {
            int b = bg * 8 + bb;
            float4 sv = *(const float4*)&sxs[b*HN+k];
            float4 pv = *(const float4*)&phs[b*HN+k];
            acc[bb] += sv.x*ux0 + sv.y*ux1 + sv.z*ux2 + sv.w*ux3
                     + pv.x*uy0 + pv.y*uy1 + pv.z*uy2 + pv.w*uy3;
        }
    }
    float bv = bd[h];
#pragma unroll
    for (int bb = 0; bb < 8; ++bb) {
        int b = bg * 8 + bb;
        float temp = acc[bb] + bv;
        oHX[b*HN+h] = tanhf(xp[b*HN+h] + temp);
        oHY[b*HN+h] = tanhf(yp[b*HN+h] + temp);
    }
}

// ===========================================================================
extern "C" void kernel_launch(void* const* d_in, const int* in_sizes, int n_in,
                              void* d_out, int out_size, void* d_ws, size_t ws_size,
                              hipStream_t stream)
{
    const float* source = (const float*)d_in[0];
    const float* target = (const float*)d_in[1];
    const float* W      = (const float*)d_in[2]; // [2][256][256]
    const float* U      = (const float*)d_in[3]; // [2][512][256]
    const float* bias   = (const float*)d_in[4]; // [2][1][256]
    float* out = (float*)d_out;

    // ws layout: xp0 [1MB] | yp0 [1MB] | zbuf [32KB zeros]
    const size_t need = 2u * 1024 * 1024 + 32768;
    bool coop_done = false;
    if (d_ws != nullptr && ws_size >= need) {
        float* xp0  = (float*)d_ws;
        float* yp0  = xp0 + 32 * BH;
        float* zbuf = yp0 + 32 * BH;
        hipMemsetAsync(zbuf, 0, 32768, stream);
        void* args[9] = {(void*)&source, (void*)&target, (void*)&W, (void*)&U,
                         (void*)&bias, (void*)&out, (void*)&xp0, (void*)&yp0,
                         (void*)&zbuf};
        hipError_t e = hipLaunchCooperativeKernel((const void*)grid_rnn_coop,
                                                  dim3(NB), dim3(256), args, 0, stream);
        if (e == hipSuccess) coop_done = true;
        else (void)hipGetLastError(); // clear sticky error, fall back
    }
    if (!coop_done) {
        // Proven round-1 ladder (scratch aliased into out[1] region).
        float* Xp0 = out + DSZ;
        float* Yp0 = Xp0 + SRCN * BH;
        proj0_kernel<<<dim3(64 * 4), dim3(256), 0, stream>>>(source, target, W, Xp0, Yp0);
        for (int t = 0; t < SRCN + TRGN - 1; ++t) {
            int nc = t + 1; if (nc > 63 - t) nc = 63 - t; if (nc > 32) nc = 32;
            diag_kernel<<<dim3(nc * 4), dim3(256), 0, stream>>>(out, U, bias, Xp0, Yp0, 0, t);
        }
        proj1_kernel<<<dim3(1024 * 4), dim3(256), 0, stream>>>(out, W + HN * HN);
        for (int t = 0; t < SRCN + TRGN - 1; ++t) {
            int nc = t + 1; if (nc > 63 - t) nc = 63 - t; if (nc > 32) nc = 32;
            diag_kernel<<<dim3(nc * 4), dim3(256), 0, stream>>>(out, U, bias, nullptr, nullptr, 1, t);
        }
    }
}

// Round 5
// 1945.969 us; speedup vs baseline: 5.1027x; 5.1027x over previous
//
#include <hip/hip_runtime.h>
#include <math.h>

// Grid-RNN (WhileOpGridLSTMNet): DEPTH=2, SRC=TRG=32, B=32, H=256
// out[d][i][j][c][b][h], c=0:HX, c=1:HY
#define SRCN 32
#define TRGN 32
#define BN   32
#define HN   256
#define BH   (BN*HN)          // 8192 floats per (cell,channel)
#define CELL (2*BH)           // 16384 floats per cell
#define DSZ  ((size_t)SRCN*TRGN*CELL) // floats per depth

__host__ __device__ __forceinline__ int ncd(int t) { // cells on diag t (0..62)
    int a = t + 1, b = 63 - t;
    int m = a < b ? a : b;
    return m < 32 ? m : 32;
}

// ---------------------------------------------------------------------------
// proj0: xp0[i] = source[i] @ W0 ; yp0[j] = target[j] @ W0   (into ws scratch)
// ---------------------------------------------------------------------------
__global__ __launch_bounds__(256) void proj0_kernel(
    const float* __restrict__ src, const float* __restrict__ trg,
    const float* __restrict__ W0, float* __restrict__ Xp0, float* __restrict__ Yp0)
{
    __shared__ float xs[BH];
    int blk = blockIdx.x >> 2, tile = blockIdx.x & 3;
    const float* X; float* P;
    if (blk < SRCN) { X = src + blk * BH; P = Xp0 + blk * BH; }
    else            { X = trg + (blk - SRCN) * BH; P = Yp0 + (blk - SRCN) * BH; }
    int tid = threadIdx.x;
    { const float4* x4 = (const float4*)X; float4* s4 = (float4*)xs;
#pragma unroll
      for (int r = 0; r < 8; ++r) s4[tid + r * 256] = x4[tid + r * 256]; }
    __syncthreads();
    int h = tile * 64 + (tid & 63), bg = tid >> 6;
    float acc[8] = {0,0,0,0,0,0,0,0};
    for (int k = 0; k < HN; k += 4) {
        float w0 = W0[(k+0)*HN+h], w1 = W0[(k+1)*HN+h], w2 = W0[(k+2)*HN+h], w3 = W0[(k+3)*HN+h];
#pragma unroll
        for (int bb = 0; bb < 8; ++bb) {
            int b = bg * 8 + bb;
            float4 xv = *(const float4*)&xs[b * HN + k];
            acc[bb] += xv.x*w0 + xv.y*w1 + xv.z*w2 + xv.w*w3;
        }
    }
#pragma unroll
    for (int bb = 0; bb < 8; ++bb) P[(bg*8+bb)*HN + h] = acc[bb];
}

// ---------------------------------------------------------------------------
// step_kernel(s): three independent block classes in ONE dispatch
//   kind 0: layer-0 recurrence, diag t=s      (n0*4 blocks)
//   kind 1: proj1 (xp1/yp1 = HX0/HY0 @ W1), diag t=s-1 (np*4 blocks)
//   kind 2: layer-1 recurrence, diag t=s-2    (n1*4 blocks)
// Cross-step ordering (incl. cross-XCD visibility) via dispatch boundaries.
// ---------------------------------------------------------------------------
__global__ __launch_bounds__(256) void step_kernel(
    const float* __restrict__ W, const float* __restrict__ U,
    const float* __restrict__ bias, float* __restrict__ out,
    const float* __restrict__ xp0, const float* __restrict__ yp0, int s)
{
    __shared__ __align__(16) float sA[BH]; // 32 KB
    __shared__ __align__(16) float sB[BH]; // 32 KB
    const int n0 = (s <= 62) ? ncd(s) : 0;
    const int np = (s >= 1 && s <= 63) ? ncd(s - 1) : 0;
    int bid = blockIdx.x;
    int kind, t;
    if (bid < n0 * 4)              { kind = 0; t = s; }
    else if (bid < (n0 + np) * 4)  { kind = 1; t = s - 1; bid -= n0 * 4; }
    else                           { kind = 2; t = s - 2; bid -= (n0 + np) * 4; }
    const int c = bid >> 2, tile = bid & 3;
    int i0 = t - 31; if (i0 < 0) i0 = 0;
    const int i = i0 + c, j = t - i;
    const size_t cOff = (size_t)(i * 32 + j) * CELL;
    const int tid = threadIdx.x;

    // ---- stage two 32x256 fp32 tiles into LDS ----
    const float *pa, *pb;
    if (kind == 0) {
        pa = (i > 0) ? out + cOff - 32 * CELL : nullptr;        // HX0[i-1,j]
        pb = (j > 0) ? out + cOff - CELL : nullptr;             // HX0[i,j-1]
    } else if (kind == 1) {
        pa = out + cOff;                                        // HX0[cell]
        pb = out + cOff + BH;                                   // HY0[cell]
    } else {
        pa = (i > 0) ? out + DSZ + cOff - 32 * CELL : nullptr;  // HX1[i-1,j]
        pb = (j > 0) ? out + DSZ + cOff - CELL : nullptr;       // HX1[i,j-1]
    }
    {
        const float4* a4 = (const float4*)pa;
        const float4* b4 = (const float4*)pb;
        float4* dA = (float4*)sA;
        float4* dB = (float4*)sB;
        const float4 z = make_float4(0.f, 0.f, 0.f, 0.f);
#pragma unroll
        for (int r = 0; r < 8; ++r) {
            int idx = tid + r * 256;
            dA[idx] = pa ? a4[idx] : z;
            dB[idx] = pb ? b4[idx] : z;
        }
    }
    __syncthreads();

    const int h  = tile * 64 + (tid & 63);
    const int bg = tid >> 6; // wave-uniform -> LDS broadcast reads

    if (kind == 1) {
        // ---- proj1: accA = HX0@W1, accB = HY0@W1 -> out[1][cell] ----
        const float* wc = W + 65536 + h;
        float accA[8] = {0,0,0,0,0,0,0,0};
        float accB[8] = {0,0,0,0,0,0,0,0};
        for (int k = 0; k < HN; k += 4) {
            float w0 = wc[(k+0)*HN], w1 = wc[(k+1)*HN];
            float w2 = wc[(k+2)*HN], w3 = wc[(k+3)*HN];
#pragma unroll
            for (int bb = 0; bb < 8; ++bb) {
                int b = bg * 8 + bb;
                float4 xv = *(const float4*)&sA[b * HN + k];
                float4 yv = *(const float4*)&sB[b * HN + k];
                accA[bb] += xv.x*w0 + xv.y*w1 + xv.z*w2 + xv.w*w3;
                accB[bb] += yv.x*w0 + yv.y*w1 + yv.z*w2 + yv.w*w3;
            }
        }
        float* xd = out + DSZ + cOff;
        float* yd = xd + BH;
#pragma unroll
        for (int bb = 0; bb < 8; ++bb) {
            int b = bg * 8 + bb;
            xd[b * HN + h] = accA[bb];
            yd[b * HN + h] = accB[bb];
        }
    } else {
        // ---- recurrence: temp = sx@Ux + ph@Uy + b; tanh epilogue ----
        const int d = (kind == 0) ? 0 : 1;
        const float* uxc = U + (size_t)d * 131072 + h;
        const float* uyc = uxc + 65536;
        float acc[8] = {0,0,0,0,0,0,0,0};
        for (int k = 0; k < HN; k += 4) {
            float x0 = uxc[(k+0)*HN], x1 = uxc[(k+1)*HN];
            float x2 = uxc[(k+2)*HN], x3 = uxc[(k+3)*HN];
            float y0 = uyc[(k+0)*HN], y1 = uyc[(k+1)*HN];
            float y2 = uyc[(k+2)*HN], y3 = uyc[(k+3)*HN];
#pragma unroll
            for (int bb = 0; bb < 8; ++bb) {
                int b = bg * 8 + bb;
                float4 sv = *(const float4*)&sA[b * HN + k];
                float4 pv = *(const float4*)&sB[b * HN + k];
                acc[bb] += sv.x*x0 + sv.y*x1 + sv.z*x2 + sv.w*x3
                         + pv.x*y0 + pv.y*y1 + pv.z*y2 + pv.w*y3;
            }
        }
        const float bv = bias[d * HN + h];
        float* oHX = out + (size_t)d * DSZ + cOff;
        float* oHY = oHX + BH;
        const float* xr = d ? oHX : (xp0 + (size_t)i * BH);
        const float* yr = d ? oHY : (yp0 + (size_t)j * BH);
#pragma unroll
        for (int bb = 0; bb < 8; ++bb) {
            int b = bg * 8 + bb;
            float tmp = acc[bb] + bv;
            // d==1: xr/yr read out[1][cell] (proj1 output) then overwrite,
            // same thread, same location -> safe.
            float xv = xr[b * HN + h];
            float yv = yr[b * HN + h];
            oHX[b * HN + h] = tanhf(xv + tmp);
            oHY[b * HN + h] = tanhf(yv + tmp);
        }
    }
}

// ===========================================================================
// Fallback (round-1, proven 3.78ms): used only if ws_size is too small.
// ===========================================================================
__global__ __launch_bounds__(256) void proj1_kernel(
    float* __restrict__ out, const float* __restrict__ W1)
{
    __shared__ float hxs[BH];
    __shared__ float hys[BH];
    int cell = blockIdx.x >> 2, tile = blockIdx.x & 3;
    const float* hx0 = out + (size_t)cell * CELL;
    const float* hy0 = hx0 + BH;
    float* xp1 = out + DSZ + (size_t)cell * CELL;
    float* yp1 = xp1 + BH;
    int tid = threadIdx.x;
    { const float4* a4 = (const float4*)hx0; const float4* b4 = (const float4*)hy0;
      float4* sa = (float4*)hxs; float4* sb = (float4*)hys;
#pragma unroll
      for (int r = 0; r < 8; ++r) { sa[tid+r*256] = a4[tid+r*256]; sb[tid+r*256] = b4[tid+r*256]; } }
    __syncthreads();
    int h = tile * 64 + (tid & 63), bg = tid >> 6;
    float ax[8] = {0,0,0,0,0,0,0,0}, ay[8] = {0,0,0,0,0,0,0,0};
    for (int k = 0; k < HN; k += 4) {
        float w0 = W1[(k+0)*HN+h], w1 = W1[(k+1)*HN+h], w2 = W1[(k+2)*HN+h], w3 = W1[(k+3)*HN+h];
#pragma unroll
        for (int bb = 0; bb < 8; ++bb) {
            int b = bg * 8 + bb;
            float4 xv = *(const float4*)&hxs[b*HN+k];
            float4 yv = *(const float4*)&hys[b*HN+k];
            ax[bb] += xv.x*w0 + xv.y*w1 + xv.z*w2 + xv.w*w3;
            ay[bb] += yv.x*w0 + yv.y*w1 + yv.z*w2 + yv.w*w3;
        }
    }
#pragma unroll
    for (int bb = 0; bb < 8; ++bb) {
        int b = bg * 8 + bb;
        xp1[b*HN+h] = ax[bb]; yp1[b*HN+h] = ay[bb];
    }
}

__global__ __launch_bounds__(256) void diag_kernel(
    float* out, const float* __restrict__ U, const float* __restrict__ bias,
    const float* __restrict__ Xp0, const float* __restrict__ Yp0, int d, int t)
{
    __shared__ float sxs[BH];
    __shared__ float phs[BH];
    int c = blockIdx.x >> 2, tile = blockIdx.x & 3;
    int i0 = t - (TRGN - 1); if (i0 < 0) i0 = 0;
    int i = i0 + c, j = t - i;
    const float* Ux = U + d * (2 * HN * HN);
    const float* Uy = Ux + HN * HN;
    float* outD = out + (size_t)d * DSZ;
    const float* sx = (i > 0) ? outD + (size_t)((i-1)*TRGN + j) * CELL : nullptr;
    const float* ph = (j > 0) ? outD + (size_t)(i*TRGN + (j-1)) * CELL : nullptr;
    float* oHX = outD + (size_t)(i*TRGN + j) * CELL;
    float* oHY = oHX + BH;
    const float* xp = d ? oHX : (Xp0 + i * BH);
    const float* yp = d ? oHY : (Yp0 + j * BH);
    const float* bd = bias + d * HN;
    int tid = threadIdx.x;
    { const float4* s4 = (const float4*)sx; const float4* p4 = (const float4*)ph;
      float4* d1 = (float4*)sxs; float4* d2 = (float4*)phs;
      float4 z = make_float4(0.f,0.f,0.f,0.f);
#pragma unroll
      for (int r = 0; r < 8; ++r) { int idx = tid + r*256; d1[idx] = sx ? s4[idx] : z; d2[idx] = ph ? p4[idx] : z; } }
    __syncthreads();
    int h = tile * 64 + (tid & 63), bg = tid >> 6;
    float acc[8] = {0,0,0,0,0,0,0,0};
    for (int k = 0; k < HN; k += 4) {
        float ux0 = Ux[(k+0)*HN+h], ux1 = Ux[(k+1)*HN+h], ux2 = Ux[(k+2)*HN+h], ux3 = Ux[(k+3)*HN+h];
        float uy0 = Uy[(k+0)*HN+h], uy1 = Uy[(k+1)*HN+h], uy2 = Uy[(k+2)*HN+h], uy3 = Uy[(k+3)*HN+h];
#pragma unroll
        for (int bb = 0; bb < 8; ++bb) {
            int b = bg * 8 + bb;
            float4 sv = *(const float4*)&sxs[b*HN+k];
            float4 pv = *(const float4*)&phs[b*HN+k];
            acc[bb] += sv.x*ux0 + sv.y*ux1 + sv.z*ux2 + sv.w*ux3
                     + pv.x*uy0 + pv.y*uy1 + pv.z*uy2 + pv.w*uy3;
        }
    }
    float bv = bd[h];
#pragma unroll
    for (int bb = 0; bb < 8; ++bb) {
        int b = bg * 8 + bb;
        float temp = acc[bb] + bv;
        oHX[b*HN+h] = tanhf(xp[b*HN+h] + temp);
        oHY[b*HN+h] = tanhf(yp[b*HN+h] + temp);
    }
}

// ===========================================================================
extern "C" void kernel_launch(void* const* d_in, const int* in_sizes, int n_in,
                              void* d_out, int out_size, void* d_ws, size_t ws_size,
                              hipStream_t stream)
{
    const float* source = (const float*)d_in[0];
    const float* target = (const float*)d_in[1];
    const float* W      = (const float*)d_in[2]; // [2][256][256]
    const float* U      = (const float*)d_in[3]; // [2][512][256]
    const float* bias   = (const float*)d_in[4]; // [2][1][256]
    float* out = (float*)d_out;

    const size_t need = 2u * 1024 * 1024; // xp0 + yp0
    if (d_ws != nullptr && ws_size >= need) {
        float* xp0 = (float*)d_ws;
        float* yp0 = xp0 + 32 * BH;
        proj0_kernel<<<dim3(64 * 4), dim3(256), 0, stream>>>(source, target, W, xp0, yp0);
        for (int s = 0; s < 65; ++s) {
            int n0 = (s <= 62) ? ncd(s) : 0;
            int np = (s >= 1 && s <= 63) ? ncd(s - 1) : 0;
            int n1 = (s >= 2) ? ncd(s - 2) : 0;
            step_kernel<<<dim3((n0 + np + n1) * 4), dim3(256), 0, stream>>>(
                W, U, bias, out, xp0, yp0, s);
        }
    } else {
        // Proven round-1 ladder (scratch aliased into out[1] region; safe
        // because proj1 runs only after ALL layer-0 diagonals).
        float* Xp0 = out + DSZ;
        float* Yp0 = Xp0 + SRCN * BH;
        proj0_kernel<<<dim3(64 * 4), dim3(256), 0, stream>>>(source, target, W, Xp0, Yp0);
        for (int t = 0; t < SRCN + TRGN - 1; ++t) {
            int nc = ncd(t);
            diag_kernel<<<dim3(nc * 4), dim3(256), 0, stream>>>(out, U, bias, Xp0, Yp0, 0, t);
        }
        proj1_kernel<<<dim3(1024 * 4), dim3(256), 0, stream>>>(out, W + HN * HN);
        for (int t = 0; t < SRCN + TRGN - 1; ++t) {
            int nc = ncd(t);
            diag_kernel<<<dim3(nc * 4), dim3(256), 0, stream>>>(out, U, bias, nullptr, nullptr, 1, t);
        }
    }
}